// Round 12
// baseline (136.100 us; speedup 1.0000x reference)
//
#include <hip/hip_runtime.h>

// Simplex projection along last dim (n = 12288), rows = 4096, fp32.
// wp = max(x - tau, 0), wc = x - wp, tau solves sum(max(x-tau,0)) = Z.
//
// LDS-STAGED, ONE ROW PER BLOCK (512 thr / 8 waves), ONE BARRIER, and
// SINGLE-STREAM PHASES (R9 vs R11 evidence: 3 concurrent global streams per
// wave = 4.3 TB/s; phase-separated = 5.88; the 1-stream fill kernel = 6.9):
//   phase 1  (1R):  x -> regs -> ds_write row to LDS + sAll + ballot-append
//                   the ~280 elements > 2.0 into per-wave LDS segments.
//   barrier  (the only one; vmcnt(0) drain harmless, loads all consumed)
//   solve:   every wave redundantly: bootstrap t in {2,3}
//            (g(t)=S_t-t*C_t >= Z  <=>  t <= tau*), Michelot on segments
//            (~4 iters, shuffle reduces) -> identical tau, no broadcast.
//            Fallback: full-row Michelot from LDS (adversarial data only).
//   phase 2a (1W):  LDS row -> wp = max(x-tau,0), PLAIN stores (fill-kernel
//                   pattern: plain store stream sustains 6.9 TB/s).
//   phase 2b (1W):  LDS row -> wc = x - wp, plain stores.
// Each wave issues long single-stream bursts; concurrent blocks mix R and W
// at the channel level stochastically.
//
// Michelot from subset start: if A0 = {x > t} with t <= tau*, every iterate
// tau_k in [t, tau*], active sets stay within A0, counts shrink to the fixed
// point; count-stable <=> exact. Validity g(t) >= Z <=> tau0 >= t.

constexpr int   N_COLS = 12288;
constexpr int   BLOCK  = 512;
constexpr int   NWAVE  = BLOCK / 64;              // 8
constexpr int   V4     = N_COLS / (BLOCK * 4);    // 6 f32x4 per thread
constexpr float Z_LVL  = 1.0f;
constexpr int   CAP_W  = 128;                     // per-wave list cap (mean 35, sd 6)
constexpr float T2     = 2.0f;
constexpr float T3     = 3.0f;

typedef float f32x4 __attribute__((ext_vector_type(4)));

struct SharedMem {
  float row[N_COLS];          // 48 KB staged row
  float seg[NWAVE][CAP_W];    // per-wave >2.0 value lists
  int   nw[NWAVE];            // per-wave list lengths
  float sAllw[NWAVE];         // per-wave full sums
};

__device__ __forceinline__ float wsum(float v) {
#pragma unroll
  for (int off = 32; off >= 1; off >>= 1) v += __shfl_xor(v, off, 64);
  return v;
}
__device__ __forceinline__ int wsumi(int v) {
#pragma unroll
  for (int off = 32; off >= 1; off >>= 1) v += __shfl_xor(v, off, 64);
  return v;
}

__global__ __launch_bounds__(BLOCK) void simplex_lds2(
    const float* __restrict__ x, float* __restrict__ wp, float* __restrict__ wc,
    int rows) {

  __shared__ SharedMem sh;

  const int tid  = threadIdx.x;
  const int lane = tid & 63;
  const int wv   = tid >> 6;
  const int row  = blockIdx.x;
  if (row >= rows) return;

  const size_t base = (size_t)row * N_COLS;
  const f32x4* __restrict__ xin = reinterpret_cast<const f32x4*>(x + base);
  f32x4* __restrict__ rowv = reinterpret_cast<f32x4*>(sh.row);

  const unsigned long long lt_mask = (lane == 0) ? 0ull : (~0ull >> (64 - lane));

  // ---- phase 1: pure-read stream -> LDS row + stats + per-wave list ----
  float sAll = 0.f;
  int   n    = 0;          // wave-uniform (SGPR) segment length
  bool  ovf  = false;

#pragma unroll
  for (int k = 0; k < V4; ++k) {
    f32x4 t = xin[tid + k * BLOCK];
    rowv[tid + k * BLOCK] = t;
#pragma unroll
    for (int j = 0; j < 4; ++j) {
      float e = t[j];
      sAll += e;
      unsigned long long m = __ballot(e > T2);
      if (m) {                              // wave-uniform, rarely taken
        int c = (int)__popcll(m);
        if (n + c <= CAP_W) {
          if (e > T2) sh.seg[wv][n + (int)__popcll(m & lt_mask)] = e;
        } else {
          ovf = true;
        }
        n += c;
      }
    }
  }
  sAll = wsum(sAll);
  if (lane == 0) { sh.nw[wv] = ovf ? -1 : n; sh.sAllw[wv] = sAll; }

  __syncthreads();   // the only barrier: row + segments + counts visible

  // ---- solve tau (every wave redundantly -> identical result) ----
  float tau  = 0.f;
  int   prev = 0;
  bool  ok   = true;
  int   ntot = 0;
  float sAllTot = 0.f;
#pragma unroll
  for (int w = 0; w < NWAVE; ++w) {
    int nwv = sh.nw[w];
    if (nwv < 0) ok = false;
    ntot += nwv;
    sAllTot += sh.sAllw[w];
  }
  ok = ok && (ntot > 0);

  if (ok) {
    float s2 = 0.f, s3 = 0.f;
    int   c3 = 0;
#pragma unroll
    for (int w = 0; w < NWAVE; ++w) {
      const int nwv = sh.nw[w];
      for (int i = lane; i < nwv; i += 64) {
        float a = sh.seg[w][i];
        s2 += a;
        bool g3 = a > T3;
        s3 += g3 ? a : 0.f;
        c3 += g3 ? 1 : 0;
      }
    }
    s2 = wsum(s2);  s3 = wsum(s3);  c3 = wsumi(c3);
    const int c2 = ntot;

    if (c3 > 0 && (s3 - 3.f * (float)c3) >= Z_LVL + 0.01f) {
      tau = (s3 - Z_LVL) / (float)c3;  prev = c3;           // tau >= 3
    } else if ((s2 - 2.f * (float)c2) >= Z_LVL + 0.01f) {
      tau = (s2 - Z_LVL) / (float)c2;  prev = c2;           // tau >= 2
    } else {
      ok = false;                                           // tau* < 2
    }

    if (ok) {
      for (int it = 0; it < 2 * CAP_W; ++it) {
        float ps = 0.f; int pc = 0;
#pragma unroll
        for (int w = 0; w < NWAVE; ++w) {
          const int nwv = sh.nw[w];
          for (int i = lane; i < nwv; i += 64) {
            float a = sh.seg[w][i];
            bool  g = a > tau;
            ps += g ? a : 0.f;
            pc += g ? 1 : 0;
          }
        }
        ps = wsum(ps);  pc = wsumi(pc);
        tau = (ps - Z_LVL) / (float)pc;
        if (pc == prev) break;                              // stable -> exact
        prev = pc;
      }
    }
  }

  if (!ok) {
    // ---- fallback (adversarial only): full-row Michelot FROM LDS ----
    tau  = (sAllTot - Z_LVL) / (float)N_COLS;
    prev = N_COLS;
    for (int it = 0; it < 100; ++it) {
      float ps = 0.f; int pc = 0;
      for (int i = lane; i < N_COLS; i += 64) {
        float a = sh.row[i];
        bool  g = a > tau;
        ps += g ? a : 0.f;
        pc += g ? 1 : 0;
      }
      ps = wsum(ps);  pc = wsumi(pc);
      tau = (ps - Z_LVL) / (float)pc;
      if (pc == prev) break;
      prev = pc;
    }
  }

  // ---- phase 2a: single write stream wp (plain stores, fill pattern) ----
  f32x4* __restrict__ wpo = reinterpret_cast<f32x4*>(wp + base);
#pragma unroll
  for (int k = 0; k < V4; ++k) {
    f32x4 t = rowv[tid + k * BLOCK];
    f32x4 pv;
#pragma unroll
    for (int j = 0; j < 4; ++j) pv[j] = fmaxf(t[j] - tau, 0.f);
    wpo[tid + k * BLOCK] = pv;
  }

  // ---- phase 2b: single write stream wc (plain stores) ----
  f32x4* __restrict__ wco = reinterpret_cast<f32x4*>(wc + base);
#pragma unroll
  for (int k = 0; k < V4; ++k) {
    f32x4 t = rowv[tid + k * BLOCK];
    f32x4 cv;
#pragma unroll
    for (int j = 0; j < 4; ++j) cv[j] = t[j] - fmaxf(t[j] - tau, 0.f);
    wco[tid + k * BLOCK] = cv;
  }
}

extern "C" void kernel_launch(void* const* d_in, const int* in_sizes, int n_in,
                              void* d_out, int out_size, void* d_ws, size_t ws_size,
                              hipStream_t stream) {
  const float* x = (const float*)d_in[0];
  const int rows = in_sizes[0] / N_COLS;

  float* wp = (float*)d_out;
  float* wc = wp + (size_t)rows * N_COLS;

  simplex_lds2<<<rows, BLOCK, 0, stream>>>(x, wp, wc, rows);
}

// Round 13
// 102.348 us; speedup vs baseline: 1.3298x; 1.3298x over previous
//
#include <hip/hip_runtime.h>

// Simplex projection along last dim (n = 12288), rows = 4096, fp32.
// wp = max(x - tau, 0), wc = x - wp, tau solves sum(max(x-tau,0)) = Z.
//
// LDS-STAGED SINGLE PASS, ONE ROW PER BLOCK (512 thr / 8 waves), ONE BARRIER.
// == R11 configuration (102.7us, best) ==
//   phase 1 (pure read): x -> regs -> ds_write row into LDS (48 KB),
//     accumulate sAll, ballot-append the ~280 elements > 2.0 into per-wave
//     LDS segments (SGPR counter + popc offsets, no atomics).
//   __syncthreads()  [only barrier; vmcnt(0) drain harmless -- loads consumed]
//   solve: every wave redundantly: bootstrap t in {2,3}
//     (g(t)=S_t-t*C_t >= Z  <=>  t <= tau*), Michelot on the segments
//     (~4 iters, shuffle reduces) -> identical tau in all waves, no broadcast.
//     Fallback: full-row Michelot FROM LDS (adversarial data only).
//   phase 2 (read LDS + 2 NT writes): compute wp/wc, NONTEMPORAL stores.
//     NT is load-bearing: plain stores write-allocate in the 4MB/XCD L2 and a
//     384MB stream thrashes it -- measured 134-136us on every plain-store
//     variant (R7/R9/R12) vs 102-110us NT (R10/R11). Do not "simplify" this.
// Global traffic: exactly 192R + 384W MB. Occupancy: 52KB LDS -> 3 blocks/CU.
// Effective rate 5.88 TB/s = 93.5% of the measured 6.29 TB/s copy ceiling.
//
// Michelot from subset start: if A0 = {x > t} with t <= tau*, every iterate
// tau_k in [t, tau*], active sets stay within A0, counts shrink to the fixed
// point; count-stable <=> exact. Validity g(t) >= Z <=> tau0 >= t.

constexpr int   N_COLS = 12288;
constexpr int   BLOCK  = 512;
constexpr int   NWAVE  = BLOCK / 64;              // 8
constexpr int   V4     = N_COLS / (BLOCK * 4);    // 6 f32x4 per thread
constexpr float Z_LVL  = 1.0f;
constexpr int   CAP_W  = 128;                     // per-wave list cap (mean 35, sd 6)
constexpr float T2     = 2.0f;
constexpr float T3     = 3.0f;

typedef float f32x4 __attribute__((ext_vector_type(4)));

struct SharedMem {
  float row[N_COLS];          // 48 KB staged row
  float seg[NWAVE][CAP_W];    // per-wave >2.0 value lists
  int   nw[NWAVE];            // per-wave list lengths
  float sAllw[NWAVE];         // per-wave full sums
};

__device__ __forceinline__ float wsum(float v) {
#pragma unroll
  for (int off = 32; off >= 1; off >>= 1) v += __shfl_xor(v, off, 64);
  return v;
}
__device__ __forceinline__ int wsumi(int v) {
#pragma unroll
  for (int off = 32; off >= 1; off >>= 1) v += __shfl_xor(v, off, 64);
  return v;
}

__global__ __launch_bounds__(BLOCK) void simplex_lds(
    const float* __restrict__ x, float* __restrict__ wp, float* __restrict__ wc,
    int rows) {

  __shared__ SharedMem sh;

  const int tid  = threadIdx.x;
  const int lane = tid & 63;
  const int wv   = tid >> 6;
  const int row  = blockIdx.x;
  if (row >= rows) return;

  const size_t base = (size_t)row * N_COLS;
  const f32x4* __restrict__ xin = reinterpret_cast<const f32x4*>(x + base);
  f32x4* __restrict__ rowv = reinterpret_cast<f32x4*>(sh.row);

  const unsigned long long lt_mask = (lane == 0) ? 0ull : (~0ull >> (64 - lane));

  // ---- phase 1: pure-read stream -> LDS row + stats + per-wave list ----
  float sAll = 0.f;
  int   n    = 0;          // wave-uniform (SGPR) segment length
  bool  ovf  = false;

#pragma unroll
  for (int k = 0; k < V4; ++k) {
    f32x4 t = xin[tid + k * BLOCK];
    rowv[tid + k * BLOCK] = t;
#pragma unroll
    for (int j = 0; j < 4; ++j) {
      float e = t[j];
      sAll += e;
      unsigned long long m = __ballot(e > T2);
      if (m) {                              // wave-uniform, rarely taken
        int c = (int)__popcll(m);
        if (n + c <= CAP_W) {
          if (e > T2) sh.seg[wv][n + (int)__popcll(m & lt_mask)] = e;
        } else {
          ovf = true;
        }
        n += c;
      }
    }
  }
  sAll = wsum(sAll);
  if (lane == 0) { sh.nw[wv] = ovf ? -1 : n; sh.sAllw[wv] = sAll; }

  __syncthreads();   // the only barrier: row + segments + counts visible

  // ---- solve tau (every wave redundantly -> identical result) ----
  float tau  = 0.f;
  int   prev = 0;
  bool  ok   = true;
  int   ntot = 0;
  float sAllTot = 0.f;
#pragma unroll
  for (int w = 0; w < NWAVE; ++w) {
    int nwv = sh.nw[w];
    if (nwv < 0) ok = false;
    ntot += nwv;
    sAllTot += sh.sAllw[w];
  }
  ok = ok && (ntot > 0);

  if (ok) {
    // stats from the segments
    float s2 = 0.f, s3 = 0.f;
    int   c3 = 0;
#pragma unroll
    for (int w = 0; w < NWAVE; ++w) {
      const int nwv = sh.nw[w];
      for (int i = lane; i < nwv; i += 64) {
        float a = sh.seg[w][i];
        s2 += a;
        bool g3 = a > T3;
        s3 += g3 ? a : 0.f;
        c3 += g3 ? 1 : 0;
      }
    }
    s2 = wsum(s2);  s3 = wsum(s3);  c3 = wsumi(c3);
    const int c2 = ntot;

    if (c3 > 0 && (s3 - 3.f * (float)c3) >= Z_LVL + 0.01f) {
      tau = (s3 - Z_LVL) / (float)c3;  prev = c3;           // tau >= 3
    } else if ((s2 - 2.f * (float)c2) >= Z_LVL + 0.01f) {
      tau = (s2 - Z_LVL) / (float)c2;  prev = c2;           // tau >= 2
    } else {
      ok = false;                                           // tau* < 2
    }

    if (ok) {
      for (int it = 0; it < 2 * CAP_W; ++it) {
        float ps = 0.f; int pc = 0;
#pragma unroll
        for (int w = 0; w < NWAVE; ++w) {
          const int nwv = sh.nw[w];
          for (int i = lane; i < nwv; i += 64) {
            float a = sh.seg[w][i];
            bool  g = a > tau;
            ps += g ? a : 0.f;
            pc += g ? 1 : 0;
          }
        }
        ps = wsum(ps);  pc = wsumi(pc);
        tau = (ps - Z_LVL) / (float)pc;
        if (pc == prev) break;                              // stable -> exact
        prev = pc;
      }
    }
  }

  if (!ok) {
    // ---- fallback (adversarial only): full-row Michelot FROM LDS ----
    tau  = (sAllTot - Z_LVL) / (float)N_COLS;
    prev = N_COLS;
    for (int it = 0; it < 100; ++it) {
      float ps = 0.f; int pc = 0;
      for (int i = lane; i < N_COLS; i += 64) {
        float a = sh.row[i];
        bool  g = a > tau;
        ps += g ? a : 0.f;
        pc += g ? 1 : 0;
      }
      ps = wsum(ps);  pc = wsumi(pc);
      tau = (ps - Z_LVL) / (float)pc;
      if (pc == prev) break;
      prev = pc;
    }
  }

  // ---- phase 2: LDS row -> compute -> NT-store wp & wc ----
  f32x4* __restrict__ wpo = reinterpret_cast<f32x4*>(wp + base);
  f32x4* __restrict__ wco = reinterpret_cast<f32x4*>(wc + base);
#pragma unroll
  for (int k = 0; k < V4; ++k) {
    f32x4 t = rowv[tid + k * BLOCK];
    f32x4 pv, cv;
#pragma unroll
    for (int j = 0; j < 4; ++j) {
      pv[j] = fmaxf(t[j] - tau, 0.f);
      cv[j] = t[j] - pv[j];
    }
    __builtin_nontemporal_store(pv, &wpo[tid + k * BLOCK]);
    __builtin_nontemporal_store(cv, &wco[tid + k * BLOCK]);
  }
}

extern "C" void kernel_launch(void* const* d_in, const int* in_sizes, int n_in,
                              void* d_out, int out_size, void* d_ws, size_t ws_size,
                              hipStream_t stream) {
  const float* x = (const float*)d_in[0];
  const int rows = in_sizes[0] / N_COLS;

  float* wp = (float*)d_out;
  float* wc = wp + (size_t)rows * N_COLS;

  simplex_lds<<<rows, BLOCK, 0, stream>>>(x, wp, wc, rows);
}